// Round 23
// baseline (175.752 us; speedup 1.0000x reference)
//
#include <hip/hip_runtime.h>
#include <stdint.h>

#define Bn 16384
#define Dn 64
#define Hn 256

typedef short bf16x8 __attribute__((ext_vector_type(8)));
typedef float f32x2 __attribute__((ext_vector_type(2)));
typedef float f32x4 __attribute__((ext_vector_type(4)));
typedef float f32x16 __attribute__((ext_vector_type(16)));

__device__ __forceinline__ unsigned f2bf1(float f) {
  unsigned u = __float_as_uint(f);
  return (u + 0x7FFFu + ((u >> 16) & 1u)) >> 16;   // RNE to bf16
}

// ---------- pack W2 into 32x32x16-fragment-linear bf16 + tail-weight transposes ----
// blocks 0..2047: Bp[d][s(16)][nb(8)][lane(64)][8 bf16]; lane holds
//   B[k = s*16+(lane>>5)*8+b][col = nb*32+(lane&31)]
// blocks 2048..2111: tail-weight transposes (merged to save a launch).
__global__ __launch_bounds__(256) void pack_all(
    const float* __restrict__ W2, unsigned short* __restrict__ Bp,
    const float* __restrict__ Wq, const float* __restrict__ Wk,
    const float* __restrict__ Wc1, const float* __restrict__ Ws,
    float* __restrict__ WqT, float* __restrict__ WkT,
    float* __restrict__ Wc1T, float* __restrict__ WsT) {
  if (blockIdx.x < 2048) {
    int gidx = blockIdx.x * 4 + (threadIdx.x >> 6);   // 8192 = 64d x 16s x 8nb
    int lane = threadIdx.x & 63;
    int d  = gidx >> 7;
    int s  = (gidx >> 3) & 15;
    int nb = gidx & 7;
    int k0 = s * 16 + ((lane >> 5) << 3);
    int n  = (nb << 5) + (lane & 31);
    const float* src = W2 + ((size_t)d * Hn + k0) * Hn + n;
    unsigned t[8];
    #pragma unroll
    for (int b = 0; b < 8; ++b) t[b] = f2bf1(src[(size_t)b * Hn]);
    uint4 w;
    w.x = t[0] | (t[1] << 16);
    w.y = t[2] | (t[3] << 16);
    w.z = t[4] | (t[5] << 16);
    w.w = t[6] | (t[7] << 16);
    size_t off = (((size_t)gidx) * 64 + lane) * 8;    // elements
    *(uint4*)(Bp + off) = w;
  } else {
    int t = (blockIdx.x - 2048) * 256 + threadIdx.x;   // 16384
    int h = t >> 6, dd = t & 63;
    WqT[dd * 256 + h]  = Wq[h * 64 + dd];
    WkT[dd * 256 + h]  = Wk[h * 64 + dd];
    Wc1T[dd * 256 + h] = Wc1[h * 64 + dd];
    WsT[h * 64 + dd]   = Ws[dd * 256 + h];
  }
}

// ---------- fused GEMM: 32x32x16 MFMA, 2 row-tiles per pass (R16, verified) ----
// 256 blocks = 8 xcd x 8 dlocal x 4 chunks, 1/CU. 512 threads = 8 waves,
// barrier-free after the B-copy: each wave owns 8 tile-PAIRS (64 rows each).
// Per pass: af0[16], af1[16] (two 32-row tiles, sharing W1/b1 loads), then
// per nb-block 16 x {ds_read bfr; mfma(bfr,af0,acc0); mfma(bfr,af1,acc1)}:
// one LDS read feeds TWO MFMAs and the two acc chains are independent.
// b2 folded into acc init; h completed in-wave (1 shfl). NEW vs R22: the
// next pass's x values are prefetched at the top of the current pass so
// their L2 latency hides under the current pass's body.
// NOTE (R17-R20 evidence): any variant adding register state (4 tiles,
// split-K accs, 2-stage epilogue pipeline, 3 waves/SIMD) crosses the
// ~256-reg/wave spill cliff and regresses 1.3-3x. This config is the
// stable optimum of the {registers, occupancy, ILP} trade-space.
__global__ __launch_bounds__(512, 1) void gemm_hcat(
    const float* __restrict__ x, const float* __restrict__ W1,
    const float* __restrict__ b1, const float* __restrict__ b2,
    const float* __restrict__ W3, const float* __restrict__ b3,
    const unsigned short* __restrict__ Bp, float* __restrict__ hcT) {
  __shared__ char Bs[131072];   // [s(16)][nb(8)][lane(64)][16B]

  int bid = blockIdx.x;
  int xcd = bid & 7;
  int dl = (bid >> 3) & 7;
  int chunk = bid >> 6;            // 0..3
  int d = xcd * 8 + dl;            // d pinned per XCD -> Bp/x L2 locality
  int base = chunk * 4096;         // 64 tile-pairs of 64 rows

  int tid = threadIdx.x;
  int lane = tid & 63;
  int w = tid >> 6;                // 0..7
  int l31 = lane & 31;
  int hsel = lane >> 5;            // k-octet group / col sub-offset

  const unsigned short* BpD = Bp + (size_t)d * 65536;
  const float* W1d = W1 + d * Hn;
  const float* b1d = b1 + d * Hn;
  const float* b2d = b2 + d * Hn;
  const float* W3d = W3 + d * Hn;
  float b3d = b3[d];

  // ---- prologue: copy packed B slice (128 KB) into LDS, linear ----
  #pragma unroll
  for (int i = 0; i < 16; ++i) {
    int idx = i * 512 + tid;                 // 16B chunks, 8192 total
    const void* g = (const void*)(BpD + (size_t)idx * 8);
    void* l = (void*)(Bs + (size_t)idx * 16);
    __builtin_amdgcn_global_load_lds((const __attribute__((address_space(1))) void*)g,
                                     (__attribute__((address_space(3))) void*)l, 16, 0, 0);
  }
  __syncthreads();   // only barrier in the kernel

  // first pass's x values
  float xv0 = x[(size_t)(base + w * 64 + l31) * Dn + d];
  float xv1 = x[(size_t)(base + w * 64 + 32 + l31) * Dn + d];

  // ---- barrier-free per-wave tile-pair loop ----
  for (int pr = w; pr < 64; pr += 8) {
    int row0 = base + pr * 64 + l31;
    int row1 = row0 + 32;

    // prefetch next pass's x (clamped on last pass; harmless re-read)
    int prn = (pr + 8 < 64) ? (pr + 8) : pr;
    float xn0 = x[(size_t)(base + prn * 64 + l31) * Dn + d];
    float xn1 = x[(size_t)(base + prn * 64 + 32 + l31) * Dn + d];

    // af0/af1: the two tiles' a1 fragments, sharing weight loads
    bf16x8 af0[16], af1[16];
    #pragma unroll
    for (int s = 0; s < 16; ++s) {
      int k = s * 16 + (hsel << 3);
      const f32x2* w1p = (const f32x2*)(W1d + k);
      const f32x2* b1p = (const f32x2*)(b1d + k);
      f32x2 wv0 = w1p[0], wv1 = w1p[1], wv2 = w1p[2], wv3 = w1p[3];
      f32x2 bv0 = b1p[0], bv1 = b1p[1], bv2 = b1p[2], bv3 = b1p[3];
      f32x2 z = {0.f, 0.f};
      {
        f32x2 xr = {xv0, xv0};
        f32x2 p0 = __builtin_elementwise_max(xr * wv0 + bv0, z);
        f32x2 p1 = __builtin_elementwise_max(xr * wv1 + bv1, z);
        f32x2 p2 = __builtin_elementwise_max(xr * wv2 + bv2, z);
        f32x2 p3 = __builtin_elementwise_max(xr * wv3 + bv3, z);
        union { uint4 u; bf16x8 v; } pk;
        asm("v_cvt_pk_bf16_f32 %0, %1, %2" : "=v"(pk.u.x) : "v"(p0.x), "v"(p0.y));
        asm("v_cvt_pk_bf16_f32 %0, %1, %2" : "=v"(pk.u.y) : "v"(p1.x), "v"(p1.y));
        asm("v_cvt_pk_bf16_f32 %0, %1, %2" : "=v"(pk.u.z) : "v"(p2.x), "v"(p2.y));
        asm("v_cvt_pk_bf16_f32 %0, %1, %2" : "=v"(pk.u.w) : "v"(p3.x), "v"(p3.y));
        af0[s] = pk.v;
      }
      {
        f32x2 xr = {xv1, xv1};
        f32x2 p0 = __builtin_elementwise_max(xr * wv0 + bv0, z);
        f32x2 p1 = __builtin_elementwise_max(xr * wv1 + bv1, z);
        f32x2 p2 = __builtin_elementwise_max(xr * wv2 + bv2, z);
        f32x2 p3 = __builtin_elementwise_max(xr * wv3 + bv3, z);
        union { uint4 u; bf16x8 v; } pk;
        asm("v_cvt_pk_bf16_f32 %0, %1, %2" : "=v"(pk.u.x) : "v"(p0.x), "v"(p0.y));
        asm("v_cvt_pk_bf16_f32 %0, %1, %2" : "=v"(pk.u.y) : "v"(p1.x), "v"(p1.y));
        asm("v_cvt_pk_bf16_f32 %0, %1, %2" : "=v"(pk.u.z) : "v"(p2.x), "v"(p2.y));
        asm("v_cvt_pk_bf16_f32 %0, %1, %2" : "=v"(pk.u.w) : "v"(p3.x), "v"(p3.y));
        af1[s] = pk.v;
      }
    }

    float ph0 = 0.f, ph1 = 0.f;
    #pragma unroll 1
    for (int nb = 0; nb < 8; ++nb) {
      int cb = (nb << 5) + (hsel << 2);      // col base incl. lane-half offset

      f32x16 acc0, acc1;
      #pragma unroll
      for (int q = 0; q < 4; ++q) {          // col = nb*32 + (r&3)+8*(r>>2)+4*hsel
        float4 bv = *(const float4*)(b2d + cb + (q << 3));
        acc0[4 * q + 0] = bv.x; acc1[4 * q + 0] = bv.x;
        acc0[4 * q + 1] = bv.y; acc1[4 * q + 1] = bv.y;
        acc0[4 * q + 2] = bv.z; acc1[4 * q + 2] = bv.z;
        acc0[4 * q + 3] = bv.w; acc1[4 * q + 3] = bv.w;
      }

      __builtin_amdgcn_s_setprio(1);
      #pragma unroll
      for (int s = 0; s < 16; ++s) {
        bf16x8 bfr = *(const bf16x8*)(Bs + ((((s << 3) + nb) << 6) + lane) * 16);
        acc0 = __builtin_amdgcn_mfma_f32_32x32x16_bf16(bfr, af0[s], acc0, 0, 0, 0);
        acc1 = __builtin_amdgcn_mfma_f32_32x32x16_bf16(bfr, af1[s], acc1, 0, 0, 0);
      }
      __builtin_amdgcn_s_setprio(0);

      #pragma unroll
      for (int q = 0; q < 4; ++q) {
        float4 wv = *(const float4*)(W3d + cb + (q << 3));
        ph0 = fmaf(fmaxf(acc0[4 * q + 0], 0.f), wv.x, ph0);
        ph0 = fmaf(fmaxf(acc0[4 * q + 1], 0.f), wv.y, ph0);
        ph0 = fmaf(fmaxf(acc0[4 * q + 2], 0.f), wv.z, ph0);
        ph0 = fmaf(fmaxf(acc0[4 * q + 3], 0.f), wv.w, ph0);
        ph1 = fmaf(fmaxf(acc1[4 * q + 0], 0.f), wv.x, ph1);
        ph1 = fmaf(fmaxf(acc1[4 * q + 1], 0.f), wv.y, ph1);
        ph1 = fmaf(fmaxf(acc1[4 * q + 2], 0.f), wv.z, ph1);
        ph1 = fmaf(fmaxf(acc1[4 * q + 3], 0.f), wv.w, ph1);
      }
    }

    ph0 += __shfl_xor(ph0, 32);              // combine the two col-halves
    ph1 += __shfl_xor(ph1, 32);
    if (lane < 32) {
      hcT[(size_t)d * Bn + row0] = ph0 + b3d;
      hcT[(size_t)d * Bn + row1] = ph1 + b3d;
    }
    xv0 = xn0;
    xv1 = xn1;
  }
}

// ---------- tail: attention fusion + cross MLP + g_func; 8 waves x 4 rows ----------
__global__ __launch_bounds__(512) void fused_tail(
    const float* __restrict__ hcT, const float* __restrict__ WqT,
    const float* __restrict__ bq, const float* __restrict__ WkT,
    const float* __restrict__ bk, const float* __restrict__ WsT,
    const float* __restrict__ bs, const float* __restrict__ Wc1T,
    const float* __restrict__ bc1, const float* __restrict__ Wc2,
    const float* __restrict__ bc2, const float* __restrict__ Wg1,
    const float* __restrict__ bg1, const float* __restrict__ Wg2,
    const float* __restrict__ bg2, float* __restrict__ out) {
  __shared__ float hcs[8][4][64];
  __shared__ float ts[8][4][256];
  int wid = threadIdx.x >> 6;                          // 0..7
  int lane = threadIdx.x & 63;
  int r0 = (blockIdx.x * 8 + wid) * 4;                 // 4 rows per wave
  float4 hc4 = *(const float4*)(hcT + (size_t)lane * Bn + r0);   // lane <-> feature d
  hcs[wid][0][lane] = hc4.x;
  hcs[wid][1][lane] = hc4.y;
  hcs[wid][2][lane] = hc4.z;
  hcs[wid][3][lane] = hc4.w;
  __syncthreads();

  float qv[4][4], kv[4][4], cv[4][4];
  #pragma unroll
  for (int j = 0; j < 4; ++j) {
    int h = lane + 64 * j;
    float bqv = bq[h], bkv = bk[h], bcv = bc1[h];
    #pragma unroll
    for (int r = 0; r < 4; ++r) { qv[r][j] = bqv; kv[r][j] = bkv; cv[r][j] = bcv; }
  }
  for (int d2 = 0; d2 < 64; ++d2) {
    float hv0 = hcs[wid][0][d2], hv1 = hcs[wid][1][d2];
    float hv2 = hcs[wid][2][d2], hv3 = hcs[wid][3][d2];
    #pragma unroll
    for (int j = 0; j < 4; ++j) {
      int h = lane + 64 * j;
      float wq = WqT[d2 * 256 + h], wk = WkT[d2 * 256 + h], wc = Wc1T[d2 * 256 + h];
      qv[0][j] = fmaf(wq, hv0, qv[0][j]); qv[1][j] = fmaf(wq, hv1, qv[1][j]);
      qv[2][j] = fmaf(wq, hv2, qv[2][j]); qv[3][j] = fmaf(wq, hv3, qv[3][j]);
      kv[0][j] = fmaf(wk, hv0, kv[0][j]); kv[1][j] = fmaf(wk, hv1, kv[1][j]);
      kv[2][j] = fmaf(wk, hv2, kv[2][j]); kv[3][j] = fmaf(wk, hv3, kv[3][j]);
      cv[0][j] = fmaf(wc, hv0, cv[0][j]); cv[1][j] = fmaf(wc, hv1, cv[1][j]);
      cv[2][j] = fmaf(wc, hv2, cv[2][j]); cv[3][j] = fmaf(wc, hv3, cv[3][j]);
    }
  }
  #pragma unroll
  for (int r = 0; r < 4; ++r)
    #pragma unroll
    for (int j = 0; j < 4; ++j)
      ts[wid][r][lane + 64 * j] = tanhf(qv[r][j] * kv[r][j]);
  __syncthreads();

  float sc[4];
  { float b = bs[lane]; sc[0] = b; sc[1] = b; sc[2] = b; sc[3] = b; }
  for (int h2 = 0; h2 < 256; ++h2) {
    float w = WsT[h2 * 64 + lane];
    sc[0] = fmaf(w, ts[wid][0][h2], sc[0]);
    sc[1] = fmaf(w, ts[wid][1][h2], sc[1]);
    sc[2] = fmaf(w, ts[wid][2][h2], sc[2]);
    sc[3] = fmaf(w, ts[wid][3][h2], sc[3]);
  }

  float hcr[4] = {hc4.x, hc4.y, hc4.z, hc4.w};
  float res[4];
  #pragma unroll
  for (int r = 0; r < 4; ++r) {
    float s = sc[r];
    float mx = s;
    #pragma unroll
    for (int off = 1; off < 64; off <<= 1) mx = fmaxf(mx, __shfl_xor(mx, off));
    float e = __expf(s - mx);
    float se = e;
    #pragma unroll
    for (int off = 1; off < 64; off <<= 1) se += __shfl_xor(se, off);
    float wgt = hcr[r] * (e / se);
    #pragma unroll
    for (int off = 1; off < 64; off <<= 1) wgt += __shfl_xor(wgt, off);
    float cp = 0.f;
    #pragma unroll
    for (int j = 0; j < 4; ++j) cp = fmaf(fmaxf(cv[r][j], 0.f), Wc2[lane + 64 * j], cp);
    #pragma unroll
    for (int off = 1; off < 64; off <<= 1) cp += __shfl_xor(cp, off);
    float comb = wgt + cp + bc2[0];
    float fp = 0.f;
    #pragma unroll
    for (int j = 0; j < 4; ++j) {
      int h = lane + 64 * j;
      fp = fmaf(fmaxf(fmaf(comb, Wg1[h], bg1[h]), 0.f), Wg2[h], fp);
    }
    #pragma unroll
    for (int off = 1; off < 64; off <<= 1) fp += __shfl_xor(fp, off);
    res[r] = fp + bg2[0];
  }
  if (lane == 0) {
    float4 o = make_float4(res[0], res[1], res[2], res[3]);
    *(float4*)(out + r0) = o;
  }
}

extern "C" void kernel_launch(void* const* d_in, const int* in_sizes, int n_in,
                              void* d_out, int out_size, void* d_ws, size_t ws_size,
                              hipStream_t stream) {
  const float* x   = (const float*)d_in[0];
  const float* W1  = (const float*)d_in[1];
  const float* b1  = (const float*)d_in[2];
  const float* W2  = (const float*)d_in[3];
  const float* b2  = (const float*)d_in[4];
  const float* W3  = (const float*)d_in[5];
  const float* b3  = (const float*)d_in[6];
  const float* Wq  = (const float*)d_in[7];
  const float* bq  = (const float*)d_in[8];
  const float* Wk  = (const float*)d_in[9];
  const float* bk  = (const float*)d_in[10];
  const float* Ws  = (const float*)d_in[11];
  const float* bs  = (const float*)d_in[12];
  const float* Wc1 = (const float*)d_in[13];
  const float* bc1 = (const float*)d_in[14];
  const float* Wc2 = (const float*)d_in[15];
  const float* bc2 = (const float*)d_in[16];
  const float* Wg1 = (const float*)d_in[17];
  const float* bg1 = (const float*)d_in[18];
  const float* Wg2 = (const float*)d_in[19];
  const float* bg2 = (const float*)d_in[20];

  unsigned short* Bp = (unsigned short*)d_ws;               // 8,388,608 B
  float* hcT  = (float*)((char*)d_ws + 8388608);            // 4,194,304 B
  float* WqT  = (float*)((char*)d_ws + 12582912);
  float* WkT  = WqT + 16384;
  float* Wc1T = WkT + 16384;
  float* WsT  = Wc1T + 16384;

  pack_all<<<2112, 256, 0, stream>>>(W2, Bp, Wq, Wk, Wc1, Ws, WqT, WkT, Wc1T, WsT);
  gemm_hcat<<<256, 512, 0, stream>>>(x, W1, b1, b2, W3, b3, Bp, hcT);
  fused_tail<<<512, 512, 0, stream>>>(hcT, WqT, bq, WkT, bk, WsT, bs, Wc1T, bc1,
                                      Wc2, bc2, Wg1, bg1, Wg2, bg2, (float*)d_out);
}

// Round 24
// 172.108 us; speedup vs baseline: 1.0212x; 1.0212x over previous
//
#include <hip/hip_runtime.h>
#include <stdint.h>

#define Bn 16384
#define Dn 64
#define Hn 256

typedef short bf16x8 __attribute__((ext_vector_type(8)));
typedef float f32x2 __attribute__((ext_vector_type(2)));
typedef float f32x4 __attribute__((ext_vector_type(4)));
typedef float f32x16 __attribute__((ext_vector_type(16)));

__device__ __forceinline__ unsigned f2bf1(float f) {
  unsigned u = __float_as_uint(f);
  return (u + 0x7FFFu + ((u >> 16) & 1u)) >> 16;   // RNE to bf16
}

// ---------- pack W2 into 32x32x16-fragment-linear bf16 + tail-weight transposes ----
__global__ __launch_bounds__(256) void pack_all(
    const float* __restrict__ W2, unsigned short* __restrict__ Bp,
    const float* __restrict__ Wq, const float* __restrict__ Wk,
    const float* __restrict__ Wc1, const float* __restrict__ Ws,
    float* __restrict__ WqT, float* __restrict__ WkT,
    float* __restrict__ Wc1T, float* __restrict__ WsT) {
  if (blockIdx.x < 2048) {
    int gidx = blockIdx.x * 4 + (threadIdx.x >> 6);   // 8192 = 64d x 16s x 8nb
    int lane = threadIdx.x & 63;
    int d  = gidx >> 7;
    int s  = (gidx >> 3) & 15;
    int nb = gidx & 7;
    int k0 = s * 16 + ((lane >> 5) << 3);
    int n  = (nb << 5) + (lane & 31);
    const float* src = W2 + ((size_t)d * Hn + k0) * Hn + n;
    unsigned t[8];
    #pragma unroll
    for (int b = 0; b < 8; ++b) t[b] = f2bf1(src[(size_t)b * Hn]);
    uint4 w;
    w.x = t[0] | (t[1] << 16);
    w.y = t[2] | (t[3] << 16);
    w.z = t[4] | (t[5] << 16);
    w.w = t[6] | (t[7] << 16);
    size_t off = (((size_t)gidx) * 64 + lane) * 8;    // elements
    *(uint4*)(Bp + off) = w;
  } else {
    int t = (blockIdx.x - 2048) * 256 + threadIdx.x;   // 16384
    int h = t >> 6, dd = t & 63;
    WqT[dd * 256 + h]  = Wq[h * 64 + dd];
    WkT[dd * 256 + h]  = Wk[h * 64 + dd];
    Wc1T[dd * 256 + h] = Wc1[h * 64 + dd];
    WsT[h * 64 + dd]   = Ws[dd * 256 + h];
  }
}

// ---------- fused GEMM: 32x32x16 MFMA, 2 row-tiles per pass ----------
// R16 structure (verified stable optimum). NEW vs R23: nb=0 is PEELED with
// the af build interleaved into its MFMA chain — MFMA s needs only af[s],
// and nb=0's MFMAs serialize on acc anyway, so the af VALU executes under
// the MFMA chain latency instead of as a serial pre-phase. Zero register
// delta (af/acc state identical); setprio dropped in the mixed cluster,
// kept for the pure nb=1..7 clusters.
__global__ __launch_bounds__(512, 1) void gemm_hcat(
    const float* __restrict__ x, const float* __restrict__ W1,
    const float* __restrict__ b1, const float* __restrict__ b2,
    const float* __restrict__ W3, const float* __restrict__ b3,
    const unsigned short* __restrict__ Bp, float* __restrict__ hcT) {
  __shared__ char Bs[131072];   // [s(16)][nb(8)][lane(64)][16B]

  int bid = blockIdx.x;
  int xcd = bid & 7;
  int dl = (bid >> 3) & 7;
  int chunk = bid >> 6;            // 0..3
  int d = xcd * 8 + dl;            // d pinned per XCD -> Bp/x L2 locality
  int base = chunk * 4096;         // 64 tile-pairs of 64 rows

  int tid = threadIdx.x;
  int lane = tid & 63;
  int w = tid >> 6;                // 0..7
  int l31 = lane & 31;
  int hsel = lane >> 5;            // k-octet group / col sub-offset

  const unsigned short* BpD = Bp + (size_t)d * 65536;
  const float* W1d = W1 + d * Hn;
  const float* b1d = b1 + d * Hn;
  const float* b2d = b2 + d * Hn;
  const float* W3d = W3 + d * Hn;
  float b3d = b3[d];

  // ---- prologue: copy packed B slice (128 KB) into LDS, linear ----
  #pragma unroll
  for (int i = 0; i < 16; ++i) {
    int idx = i * 512 + tid;                 // 16B chunks, 8192 total
    const void* g = (const void*)(BpD + (size_t)idx * 8);
    void* l = (void*)(Bs + (size_t)idx * 16);
    __builtin_amdgcn_global_load_lds((const __attribute__((address_space(1))) void*)g,
                                     (__attribute__((address_space(3))) void*)l, 16, 0, 0);
  }
  __syncthreads();   // only barrier in the kernel

  // ---- barrier-free per-wave tile-pair loop ----
  for (int pr = w; pr < 64; pr += 8) {
    int row0 = base + pr * 64 + l31;
    int row1 = row0 + 32;
    float xv0 = x[(size_t)row0 * Dn + d];
    float xv1 = x[(size_t)row1 * Dn + d];

    bf16x8 af0[16], af1[16];
    float ph0 = 0.f, ph1 = 0.f;

    // ---- peeled nb = 0: af build interleaved into the MFMA chain ----
    {
      int cb = (hsel << 2);
      f32x16 acc0, acc1;
      #pragma unroll
      for (int q = 0; q < 4; ++q) {
        float4 bv = *(const float4*)(b2d + cb + (q << 3));
        acc0[4 * q + 0] = bv.x; acc1[4 * q + 0] = bv.x;
        acc0[4 * q + 1] = bv.y; acc1[4 * q + 1] = bv.y;
        acc0[4 * q + 2] = bv.z; acc1[4 * q + 2] = bv.z;
        acc0[4 * q + 3] = bv.w; acc1[4 * q + 3] = bv.w;
      }

      #pragma unroll
      for (int s = 0; s < 16; ++s) {
        int k = s * 16 + (hsel << 3);
        const f32x2* w1p = (const f32x2*)(W1d + k);
        const f32x2* b1p = (const f32x2*)(b1d + k);
        f32x2 wv0 = w1p[0], wv1 = w1p[1], wv2 = w1p[2], wv3 = w1p[3];
        f32x2 bv0 = b1p[0], bv1 = b1p[1], bv2 = b1p[2], bv3 = b1p[3];
        f32x2 z = {0.f, 0.f};
        {
          f32x2 xr = {xv0, xv0};
          f32x2 p0 = __builtin_elementwise_max(xr * wv0 + bv0, z);
          f32x2 p1 = __builtin_elementwise_max(xr * wv1 + bv1, z);
          f32x2 p2 = __builtin_elementwise_max(xr * wv2 + bv2, z);
          f32x2 p3 = __builtin_elementwise_max(xr * wv3 + bv3, z);
          union { uint4 u; bf16x8 v; } pk;
          asm("v_cvt_pk_bf16_f32 %0, %1, %2" : "=v"(pk.u.x) : "v"(p0.x), "v"(p0.y));
          asm("v_cvt_pk_bf16_f32 %0, %1, %2" : "=v"(pk.u.y) : "v"(p1.x), "v"(p1.y));
          asm("v_cvt_pk_bf16_f32 %0, %1, %2" : "=v"(pk.u.z) : "v"(p2.x), "v"(p2.y));
          asm("v_cvt_pk_bf16_f32 %0, %1, %2" : "=v"(pk.u.w) : "v"(p3.x), "v"(p3.y));
          af0[s] = pk.v;
        }
        {
          f32x2 xr = {xv1, xv1};
          f32x2 p0 = __builtin_elementwise_max(xr * wv0 + bv0, z);
          f32x2 p1 = __builtin_elementwise_max(xr * wv1 + bv1, z);
          f32x2 p2 = __builtin_elementwise_max(xr * wv2 + bv2, z);
          f32x2 p3 = __builtin_elementwise_max(xr * wv3 + bv3, z);
          union { uint4 u; bf16x8 v; } pk;
          asm("v_cvt_pk_bf16_f32 %0, %1, %2" : "=v"(pk.u.x) : "v"(p0.x), "v"(p0.y));
          asm("v_cvt_pk_bf16_f32 %0, %1, %2" : "=v"(pk.u.y) : "v"(p1.x), "v"(p1.y));
          asm("v_cvt_pk_bf16_f32 %0, %1, %2" : "=v"(pk.u.z) : "v"(p2.x), "v"(p2.y));
          asm("v_cvt_pk_bf16_f32 %0, %1, %2" : "=v"(pk.u.w) : "v"(p3.x), "v"(p3.y));
          af1[s] = pk.v;
        }
        bf16x8 bfr = *(const bf16x8*)(Bs + (((s << 9) + lane) << 4));
        acc0 = __builtin_amdgcn_mfma_f32_32x32x16_bf16(bfr, af0[s], acc0, 0, 0, 0);
        acc1 = __builtin_amdgcn_mfma_f32_32x32x16_bf16(bfr, af1[s], acc1, 0, 0, 0);
      }

      #pragma unroll
      for (int q = 0; q < 4; ++q) {
        float4 wv = *(const float4*)(W3d + cb + (q << 3));
        ph0 = fmaf(fmaxf(acc0[4 * q + 0], 0.f), wv.x, ph0);
        ph0 = fmaf(fmaxf(acc0[4 * q + 1], 0.f), wv.y, ph0);
        ph0 = fmaf(fmaxf(acc0[4 * q + 2], 0.f), wv.z, ph0);
        ph0 = fmaf(fmaxf(acc0[4 * q + 3], 0.f), wv.w, ph0);
        ph1 = fmaf(fmaxf(acc1[4 * q + 0], 0.f), wv.x, ph1);
        ph1 = fmaf(fmaxf(acc1[4 * q + 1], 0.f), wv.y, ph1);
        ph1 = fmaf(fmaxf(acc1[4 * q + 2], 0.f), wv.z, ph1);
        ph1 = fmaf(fmaxf(acc1[4 * q + 3], 0.f), wv.w, ph1);
      }
    }

    // ---- nb = 1..7: pure MFMA clusters on the materialized af ----
    #pragma unroll 1
    for (int nb = 1; nb < 8; ++nb) {
      int cb = (nb << 5) + (hsel << 2);

      f32x16 acc0, acc1;
      #pragma unroll
      for (int q = 0; q < 4; ++q) {
        float4 bv = *(const float4*)(b2d + cb + (q << 3));
        acc0[4 * q + 0] = bv.x; acc1[4 * q + 0] = bv.x;
        acc0[4 * q + 1] = bv.y; acc1[4 * q + 1] = bv.y;
        acc0[4 * q + 2] = bv.z; acc1[4 * q + 2] = bv.z;
        acc0[4 * q + 3] = bv.w; acc1[4 * q + 3] = bv.w;
      }

      __builtin_amdgcn_s_setprio(1);
      #pragma unroll
      for (int s = 0; s < 16; ++s) {
        bf16x8 bfr = *(const bf16x8*)(Bs + ((((s << 3) + nb) << 6) + lane) * 16);
        acc0 = __builtin_amdgcn_mfma_f32_32x32x16_bf16(bfr, af0[s], acc0, 0, 0, 0);
        acc1 = __builtin_amdgcn_mfma_f32_32x32x16_bf16(bfr, af1[s], acc1, 0, 0, 0);
      }
      __builtin_amdgcn_s_setprio(0);

      #pragma unroll
      for (int q = 0; q < 4; ++q) {
        float4 wv = *(const float4*)(W3d + cb + (q << 3));
        ph0 = fmaf(fmaxf(acc0[4 * q + 0], 0.f), wv.x, ph0);
        ph0 = fmaf(fmaxf(acc0[4 * q + 1], 0.f), wv.y, ph0);
        ph0 = fmaf(fmaxf(acc0[4 * q + 2], 0.f), wv.z, ph0);
        ph0 = fmaf(fmaxf(acc0[4 * q + 3], 0.f), wv.w, ph0);
        ph1 = fmaf(fmaxf(acc1[4 * q + 0], 0.f), wv.x, ph1);
        ph1 = fmaf(fmaxf(acc1[4 * q + 1], 0.f), wv.y, ph1);
        ph1 = fmaf(fmaxf(acc1[4 * q + 2], 0.f), wv.z, ph1);
        ph1 = fmaf(fmaxf(acc1[4 * q + 3], 0.f), wv.w, ph1);
      }
    }

    ph0 += __shfl_xor(ph0, 32);              // combine the two col-halves
    ph1 += __shfl_xor(ph1, 32);
    if (lane < 32) {
      hcT[(size_t)d * Bn + row0] = ph0 + b3d;
      hcT[(size_t)d * Bn + row1] = ph1 + b3d;
    }
  }
}

// ---------- tail: attention fusion + cross MLP + g_func; 8 waves x 4 rows ----------
__global__ __launch_bounds__(512) void fused_tail(
    const float* __restrict__ hcT, const float* __restrict__ WqT,
    const float* __restrict__ bq, const float* __restrict__ WkT,
    const float* __restrict__ bk, const float* __restrict__ WsT,
    const float* __restrict__ bs, const float* __restrict__ Wc1T,
    const float* __restrict__ bc1, const float* __restrict__ Wc2,
    const float* __restrict__ bc2, const float* __restrict__ Wg1,
    const float* __restrict__ bg1, const float* __restrict__ Wg2,
    const float* __restrict__ bg2, float* __restrict__ out) {
  __shared__ float hcs[8][4][64];
  __shared__ float ts[8][4][256];
  int wid = threadIdx.x >> 6;                          // 0..7
  int lane = threadIdx.x & 63;
  int r0 = (blockIdx.x * 8 + wid) * 4;                 // 4 rows per wave
  float4 hc4 = *(const float4*)(hcT + (size_t)lane * Bn + r0);   // lane <-> feature d
  hcs[wid][0][lane] = hc4.x;
  hcs[wid][1][lane] = hc4.y;
  hcs[wid][2][lane] = hc4.z;
  hcs[wid][3][lane] = hc4.w;
  __syncthreads();

  float qv[4][4], kv[4][4], cv[4][4];
  #pragma unroll
  for (int j = 0; j < 4; ++j) {
    int h = lane + 64 * j;
    float bqv = bq[h], bkv = bk[h], bcv = bc1[h];
    #pragma unroll
    for (int r = 0; r < 4; ++r) { qv[r][j] = bqv; kv[r][j] = bkv; cv[r][j] = bcv; }
  }
  for (int d2 = 0; d2 < 64; ++d2) {
    float hv0 = hcs[wid][0][d2], hv1 = hcs[wid][1][d2];
    float hv2 = hcs[wid][2][d2], hv3 = hcs[wid][3][d2];
    #pragma unroll
    for (int j = 0; j < 4; ++j) {
      int h = lane + 64 * j;
      float wq = WqT[d2 * 256 + h], wk = WkT[d2 * 256 + h], wc = Wc1T[d2 * 256 + h];
      qv[0][j] = fmaf(wq, hv0, qv[0][j]); qv[1][j] = fmaf(wq, hv1, qv[1][j]);
      qv[2][j] = fmaf(wq, hv2, qv[2][j]); qv[3][j] = fmaf(wq, hv3, qv[3][j]);
      kv[0][j] = fmaf(wk, hv0, kv[0][j]); kv[1][j] = fmaf(wk, hv1, kv[1][j]);
      kv[2][j] = fmaf(wk, hv2, kv[2][j]); kv[3][j] = fmaf(wk, hv3, kv[3][j]);
      cv[0][j] = fmaf(wc, hv0, cv[0][j]); cv[1][j] = fmaf(wc, hv1, cv[1][j]);
      cv[2][j] = fmaf(wc, hv2, cv[2][j]); cv[3][j] = fmaf(wc, hv3, cv[3][j]);
    }
  }
  #pragma unroll
  for (int r = 0; r < 4; ++r)
    #pragma unroll
    for (int j = 0; j < 4; ++j)
      ts[wid][r][lane + 64 * j] = tanhf(qv[r][j] * kv[r][j]);
  __syncthreads();

  float sc[4];
  { float b = bs[lane]; sc[0] = b; sc[1] = b; sc[2] = b; sc[3] = b; }
  for (int h2 = 0; h2 < 256; ++h2) {
    float w = WsT[h2 * 64 + lane];
    sc[0] = fmaf(w, ts[wid][0][h2], sc[0]);
    sc[1] = fmaf(w, ts[wid][1][h2], sc[1]);
    sc[2] = fmaf(w, ts[wid][2][h2], sc[2]);
    sc[3] = fmaf(w, ts[wid][3][h2], sc[3]);
  }

  float hcr[4] = {hc4.x, hc4.y, hc4.z, hc4.w};
  float res[4];
  #pragma unroll
  for (int r = 0; r < 4; ++r) {
    float s = sc[r];
    float mx = s;
    #pragma unroll
    for (int off = 1; off < 64; off <<= 1) mx = fmaxf(mx, __shfl_xor(mx, off));
    float e = __expf(s - mx);
    float se = e;
    #pragma unroll
    for (int off = 1; off < 64; off <<= 1) se += __shfl_xor(se, off);
    float wgt = hcr[r] * (e / se);
    #pragma unroll
    for (int off = 1; off < 64; off <<= 1) wgt += __shfl_xor(wgt, off);
    float cp = 0.f;
    #pragma unroll
    for (int j = 0; j < 4; ++j) cp = fmaf(fmaxf(cv[r][j], 0.f), Wc2[lane + 64 * j], cp);
    #pragma unroll
    for (int off = 1; off < 64; off <<= 1) cp += __shfl_xor(cp, off);
    float comb = wgt + cp + bc2[0];
    float fp = 0.f;
    #pragma unroll
    for (int j = 0; j < 4; ++j) {
      int h = lane + 64 * j;
      fp = fmaf(fmaxf(fmaf(comb, Wg1[h], bg1[h]), 0.f), Wg2[h], fp);
    }
    #pragma unroll
    for (int off = 1; off < 64; off <<= 1) fp += __shfl_xor(fp, off);
    res[r] = fp + bg2[0];
  }
  if (lane == 0) {
    float4 o = make_float4(res[0], res[1], res[2], res[3]);
    *(float4*)(out + r0) = o;
  }
}

extern "C" void kernel_launch(void* const* d_in, const int* in_sizes, int n_in,
                              void* d_out, int out_size, void* d_ws, size_t ws_size,
                              hipStream_t stream) {
  const float* x   = (const float*)d_in[0];
  const float* W1  = (const float*)d_in[1];
  const float* b1  = (const float*)d_in[2];
  const float* W2  = (const float*)d_in[3];
  const float* b2  = (const float*)d_in[4];
  const float* W3  = (const float*)d_in[5];
  const float* b3  = (const float*)d_in[6];
  const float* Wq  = (const float*)d_in[7];
  const float* bq  = (const float*)d_in[8];
  const float* Wk  = (const float*)d_in[9];
  const float* bk  = (const float*)d_in[10];
  const float* Ws  = (const float*)d_in[11];
  const float* bs  = (const float*)d_in[12];
  const float* Wc1 = (const float*)d_in[13];
  const float* bc1 = (const float*)d_in[14];
  const float* Wc2 = (const float*)d_in[15];
  const float* bc2 = (const float*)d_in[16];
  const float* Wg1 = (const float*)d_in[17];
  const float* bg1 = (const float*)d_in[18];
  const float* Wg2 = (const float*)d_in[19];
  const float* bg2 = (const float*)d_in[20];

  unsigned short* Bp = (unsigned short*)d_ws;               // 8,388,608 B
  float* hcT  = (float*)((char*)d_ws + 8388608);            // 4,194,304 B
  float* WqT  = (float*)((char*)d_ws + 12582912);
  float* WkT  = WqT + 16384;
  float* Wc1T = WkT + 16384;
  float* WsT  = Wc1T + 16384;

  pack_all<<<2112, 256, 0, stream>>>(W2, Bp, Wq, Wk, Wc1, Ws, WqT, WkT, Wc1T, WsT);
  gemm_hcat<<<256, 512, 0, stream>>>(x, W1, b1, b2, W3, b3, Bp, hcT);
  fused_tail<<<512, 512, 0, stream>>>(hcT, WqT, bq, WkT, bk, WsT, bs, Wc1T, bc1,
                                      Wc2, bc2, Wg1, bg1, Wg2, bg2, (float*)d_out);
}